// Round 5
// baseline (1391.936 us; speedup 1.0000x reference)
//
#include <hip/hip_runtime.h>

// GeometryTransformation: backproject(theta=0) -> 2x resblock(conv3d 16->16 3^3,
// InstanceNorm, ReLU, residual) -> forward-project at theta in {0, pi/2}.
//
// Round-5 structure: elementwise math (IN + ReLU + residual) is hoisted out of
// the latency-critical conv into streaming kernels:
//   bcast_k: vol0[d][y][x][c] = proj[c][d][y]              (64MB write)
//   conv_k:  pure conv+bias+fused-stats, staging = raw copy (no VALU unpack)
//   norm_k:  out = relu((raw-m)*s [+ res])                  (streaming, 1x/voxel)
//   fproj_k: vol2 = relu((y4-m3)s3 + xb), row/col sums (xb read pre-materialized)
// Conv: tile 4z x 8y x 16x, halo 6x10x18 (34.6KB LDS -> 4 blocks/CU),
// K = kx{0,1 | 2,pad} x 16ci, frag1 column clamped to 17 (pad A-weights are 0).
//
// Verified identities (rounds 2-4 passed):
//   backproject: vol0[c,d,y,x] = proj[c,0,d,y]
//   fproj 0:     out[c,0,d,i] = sum_x vol2[c,d,i,x]
//   fproj pi/2:  out[c,1,d,i] = sum_y vol2[c,d,y,i], EXCEPT i==0 sums y<64 only.

typedef unsigned short u16;
typedef unsigned int   u32;
using s16x8 = __attribute__((ext_vector_type(8))) short;
using f32x4 = __attribute__((ext_vector_type(4))) float;

#define NV        (1 << 21)
#define VOL_ELEMS (16 * NV)
#define WS_NEED   (3ull * VOL_ELEMS * 2ull + 4096ull)

__device__ __forceinline__ float bf2f(u16 h) {
    union { u32 u; float f; } v; v.u = ((u32)h) << 16; return v.f;
}
__device__ __forceinline__ u16 f2bf(float f) {
    union { float f; u32 u; } v; v.f = f;
    u32 u = v.u;
    return (u16)((u + 0x7fffu + ((u >> 16) & 1u)) >> 16);
}
__device__ __forceinline__ float ldin(const void* p, int i, int bf) {
    return bf ? bf2f(((const u16*)p)[i]) : ((const float*)p)[i];
}
__device__ __forceinline__ u16 ldbf(const void* p, int i, int bf) {
    return bf ? ((const u16*)p)[i] : f2bf(((const float*)p)[i]);
}
__device__ __forceinline__ void unpack16(uint4 a, uint4 b, float* f) {
    u32 w[8] = {a.x, a.y, a.z, a.w, b.x, b.y, b.z, b.w};
#pragma unroll
    for (int i = 0; i < 8; i++) {
        f[2*i]   = bf2f((u16)(w[i] & 0xffff));
        f[2*i+1] = bf2f((u16)(w[i] >> 16));
    }
}

// stats zero + dtype sniff (bf16 vs fp32) from w_a1 bit patterns.
__global__ void init_k(const void* __restrict__ w, float* __restrict__ st,
                       int* __restrict__ flag)
{
    const int tid = threadIdx.x;
    for (int i = tid; i < 256; i += 64) st[i] = 0.f;
    if (tid == 0) {
        const u16* p = (const u16*)w;
        int cnt = 0;
        for (int i = 0; i < 32; i++) {
            int e = (p[2 * i] >> 7) & 0xFF;
            if (e >= 64 && e <= 130) cnt++;
        }
        *flag = (cnt >= 24) ? 1 : 0;
    }
}

__global__ void sentinel_k(u16* __restrict__ out, int n)
{
    int i = blockIdx.x * 256 + threadIdx.x;
    if (i < n) out[i] = 0x4640;
}

// vol0[d][y][x][c] = proj[c][row]; block = 2 rows x 128 x.
__global__ __launch_bounds__(256) void bcast_k(const void* __restrict__ proj,
                                               const int* __restrict__ flagp,
                                               u16* __restrict__ out)
{
    __shared__ float pf[2][16];
    const int bf = *flagp;
    const int tid = threadIdx.x;
    const int row0 = blockIdx.x * 2;
    if (tid < 32) {
        int r = tid >> 4, ci = tid & 15;
        pf[r][ci] = ldin(proj, ci * 16384 + row0 + r, bf);
    }
    __syncthreads();
    const int r = tid >> 7, x = tid & 127;
    const float* f = pf[r];
    u32 pw[8];
#pragma unroll
    for (int j = 0; j < 8; j++)
        pw[j] = (u32)f2bf(f[2*j]) | ((u32)f2bf(f[2*j+1]) << 16);
    uint4* dst = (uint4*)(out + ((((row0 + r) << 7) + x) << 4));
    dst[0] = make_uint4(pw[0], pw[1], pw[2], pw[3]);
    dst[1] = make_uint4(pw[4], pw[5], pw[6], pw[7]);
}

// Streaming normalize: outn = relu((raw - m)*s + (RES ? res : 0)). 1 voxel/thread.
template <int RES>
__global__ __launch_bounds__(256) void norm_k(const u16* __restrict__ raw,
                                              const u16* __restrict__ res,
                                              const float* __restrict__ st,
                                              u16* __restrict__ outn)
{
    __shared__ float sA[32];
    const int tid = threadIdx.x;
    if (tid < 16)      sA[tid] = st[32 + tid];
    else if (tid < 32) sA[tid] = st[48 + (tid - 16)];
    __syncthreads();
    const int v = blockIdx.x * 256 + tid;
    const uint4* pr = (const uint4*)(raw + (v << 4));
    float f[16];
    unpack16(pr[0], pr[1], f);
    float rv[16];
    if (RES) {
        const uint4* pb = (const uint4*)(res + (v << 4));
        unpack16(pb[0], pb[1], rv);
    }
#pragma unroll
    for (int j = 0; j < 16; j++) {
        float z = (f[j] - sA[j]) * sA[16 + j] + (RES ? rv[j] : 0.f);
        f[j] = fmaxf(z, 0.f);
    }
    u32 pw[8];
#pragma unroll
    for (int j = 0; j < 8; j++)
        pw[j] = (u32)f2bf(f[2*j]) | ((u32)f2bf(f[2*j+1]) << 16);
    uint4* dst = (uint4*)(outn + (v << 4));
    dst[0] = make_uint4(pw[0], pw[1], pw[2], pw[3]);
    dst[1] = make_uint4(pw[4], pw[5], pw[6], pw[7]);
}

// ---------------------------------------------------------------------------
// Pure MFMA conv + bias + fused stats. Input is an already-normalized volume.
// Block tile 4z x 8y x 16x (256 thr, wave w -> z-slice d0+w, 8 y-accs).
// Halo 6z x 10y x 18x voxels in LDS as uint4 tile[z][y][h][x18].
// K-packing: k = kx*16+ci; frag0 = kx{0,1}, frag1 = kx{2,pad(A=0)}.
// Lane l: n=l&15 (co / out-x), g=l>>4, h=g&1 (ci half), kxs=g>>1 (kx parity).
// frag0 col = n+kxs (<=16); frag1 col = min(n+kxs+2, 17) (clamp valid: A=0 there).
// ---------------------------------------------------------------------------
__global__ __launch_bounds__(256, 4) void conv_k(
    const u16*  __restrict__ vin,   // normalized input volume [d][y][x][c]
    const void* __restrict__ wgt,   // (co,ci,3,3,3)
    const void* __restrict__ bias,  // (16,)
    const int*  __restrict__ flagp,
    u16* __restrict__ out,          // raw conv+bias out [d][y][x][c]
    float* __restrict__ st_out)     // stat sums at [0..31]
{
    __shared__ uint4 tile[2160];    // 34.56 KB  [z6][y10][h2][x18]
    __shared__ float sred[32];
    const int bf  = *flagp;
    const int tid = threadIdx.x;
    const int l   = tid & 63;
    const int w   = tid >> 6;
    const int n   = l & 15;
    const int g   = l >> 4;
    const int h   = g & 1;
    const int kxs = g >> 1;

    const int x0 = blockIdx.x * 16;
    const int y0 = blockIdx.y * 8;
    const int d0 = blockIdx.z * 4;

    if (tid < 32) sred[tid] = 0.f;

    // stage halo: pure copy, coalesced along (x,h)
    for (int u = tid; u < 2160; u += 256) {
        int z = u / 360, r1 = u - z * 360;
        int y = r1 / 36,  r2 = r1 - y * 36;
        int x = r2 >> 1,  hh = r2 & 1;
        int gz = d0 + z - 1, gy = y0 + y - 1, gx = x0 + x - 1;
        uint4 val = make_uint4(0u, 0u, 0u, 0u);
        if ((unsigned)gz < 128u && (unsigned)gy < 128u && (unsigned)gx < 128u)
            val = *(const uint4*)(vin + (((((gz << 7) + gy) << 7) + gx) << 4) + hh * 8);
        tile[((z * 10 + y) * 2 + hh) * 18 + x] = val;
    }

    // A-fragments (weights), loaded while staging is in flight
    s16x8 af[3][3][2];
#pragma unroll
    for (int kz = 0; kz < 3; kz++)
#pragma unroll
        for (int ky = 0; ky < 3; ky++)
#pragma unroll
            for (int grp = 0; grp < 2; grp++) {
                int kx = grp * 2 + kxs;     // 0,1 | 2,3(pad)
                s16x8 a;
#pragma unroll
                for (int e = 0; e < 8; e++) {
                    int ci = h * 8 + e;
                    u16 wv = 0;
                    if (kx <= 2)
                        wv = ldbf(wgt, n * 432 + ci * 27 + kz * 9 + ky * 3 + kx, bf);
                    a[e] = (short)wv;
                }
                af[kz][ky][grp] = a;
            }
    f32x4 binit;
#pragma unroll
    for (int r = 0; r < 4; r++) binit[r] = ldin(bias, g * 4 + r, bf);

    __syncthreads();

    f32x4 acc[8];
#pragma unroll
    for (int yl = 0; yl < 8; yl++) acc[yl] = binit;

    const int c0 = n + kxs;
    const int c1 = (c0 + 2 > 17) ? 17 : (c0 + 2);
#pragma unroll
    for (int kz = 0; kz < 3; kz++) {
        const int zt = w + kz;
#pragma unroll
        for (int yin = 0; yin < 10; yin++) {
            const int base = ((zt * 10 + yin) * 2 + h) * 18;
            s16x8 f0 = __builtin_bit_cast(s16x8, tile[base + c0]);
            s16x8 f1 = __builtin_bit_cast(s16x8, tile[base + c1]);
#pragma unroll
            for (int ky = 0; ky < 3; ky++) {
                const int yl = yin - ky;
                if (yl >= 0 && yl < 8)
                    acc[yl] = __builtin_amdgcn_mfma_f32_16x16x32_bf16(af[kz][ky][0], f0, acc[yl], 0, 0, 0);
            }
#pragma unroll
            for (int ky = 0; ky < 3; ky++) {
                const int yl = yin - ky;
                if (yl >= 0 && yl < 8)
                    acc[yl] = __builtin_amdgcn_mfma_f32_16x16x32_bf16(af[kz][ky][1], f1, acc[yl], 0, 0, 0);
            }
        }
    }

    // epilogue: store (D: col=lane&15 -> x, row=g*4+r -> co) + fused stats
    float sr[4] = {0.f, 0.f, 0.f, 0.f}, qr[4] = {0.f, 0.f, 0.f, 0.f};
    const int gz = d0 + w;
#pragma unroll
    for (int yl = 0; yl < 8; yl++) {
        const int gy = y0 + yl;
        u32 lo = (u32)f2bf(acc[yl][0]) | ((u32)f2bf(acc[yl][1]) << 16);
        u32 hi = (u32)f2bf(acc[yl][2]) | ((u32)f2bf(acc[yl][3]) << 16);
        *(uint2*)(out + (((((gz << 7) + gy) << 7) + (x0 + n)) << 4) + g * 4) =
            make_uint2(lo, hi);
#pragma unroll
        for (int r = 0; r < 4; r++) {
            sr[r] += acc[yl][r];
            qr[r] = fmaf(acc[yl][r], acc[yl][r], qr[r]);
        }
    }
#pragma unroll
    for (int off = 1; off < 16; off <<= 1) {
#pragma unroll
        for (int r = 0; r < 4; r++) {
            sr[r] += __shfl_down(sr[r], off, 16);
            qr[r] += __shfl_down(qr[r], off, 16);
        }
    }
    if (n == 0) {
#pragma unroll
        for (int r = 0; r < 4; r++) {
            atomicAdd(&sred[g * 4 + r], sr[r]);
            atomicAdd(&sred[16 + g * 4 + r], qr[r]);
        }
    }
    __syncthreads();
    if (tid < 32) atomicAdd(&st_out[tid], sred[tid]);
}

__global__ void finalize_k(float* st)
{
    const int c = threadIdx.x;
    if (c < 16) {
        const float inv = 1.f / 2097152.f;
        float m = st[c] * inv;
        float v = st[16 + c] * inv - m * m;
        st[32 + c] = m;
        st[48 + c] = rsqrtf(v + 1e-5f);
    }
}

// fproj: block per d. vol2 = relu((y4-m3)s3 + xb) with xb pre-materialized.
// Rows via shfl-reduce; cols via register accumulators. x==0 col sums y<64 only.
__global__ __launch_bounds__(256) void fproj_k(
    const u16* __restrict__ y4, const u16* __restrict__ xb,
    const float* __restrict__ st, const int* __restrict__ flagp,
    void* __restrict__ out)
{
    __shared__ float sbuf[8 * 128 * 16];
    __shared__ float sA[32];
    const int bf = *flagp;
    const int d = blockIdx.x;
    const int tid = threadIdx.x;
    if (tid < 16)      sA[tid] = st[192 + 32 + tid];
    else if (tid < 32) sA[tid] = st[192 + 48 + (tid - 16)];
    __syncthreads();

    const int y_loc = tid >> 5, xg = tid & 31;
    const int xB = tid >> 1, chalf = tid & 1;
    float colr[8], colr0[8];
#pragma unroll
    for (int j = 0; j < 8; j++) { colr[j] = 0.f; colr0[j] = 0.f; }

    for (int s = 0; s < 16; s++) {
        const int y = s * 8 + y_loc;
        float rowp[16];
#pragma unroll
        for (int ci = 0; ci < 16; ci++) rowp[ci] = 0.f;
        for (int i = 0; i < 4; i++) {
            const int x = xg + i * 32;
            const int e = ((d * 128 + y) * 128 + x) * 16;
            const uint4* p4 = (const uint4*)(y4 + e);
            const uint4* pb = (const uint4*)(xb + e);
            float f4a[16], fxb[16];
            unpack16(p4[0], p4[1], f4a);
            unpack16(pb[0], pb[1], fxb);
            float* sb = &sbuf[(y_loc * 128 + x) * 16];
#pragma unroll
            for (int ci = 0; ci < 16; ci++) {
                float v = fmaxf((f4a[ci] - sA[ci]) * sA[16 + ci] + fxb[ci], 0.f);
                rowp[ci] += v;
                sb[ci] = v;
            }
        }
#pragma unroll
        for (int ci = 0; ci < 16; ci++) {
            float rv = rowp[ci];
            rv += __shfl_down(rv, 1, 32);
            rv += __shfl_down(rv, 2, 32);
            rv += __shfl_down(rv, 4, 32);
            rv += __shfl_down(rv, 8, 32);
            rv += __shfl_down(rv, 16, 32);
            rowp[ci] = rv;
        }
        if (xg == 0) {
#pragma unroll
            for (int ci = 0; ci < 16; ci++) {
                int oi = (ci * 2 + 0) * 16384 + d * 128 + y;
                if (bf) ((u16*)out)[oi] = f2bf(rowp[ci]);
                else    ((float*)out)[oi] = rowp[ci];
            }
        }
        __syncthreads();
#pragma unroll
        for (int yl = 0; yl < 8; yl++) {
#pragma unroll
            for (int j = 0; j < 8; j++) {
                float v = sbuf[(yl * 128 + xB) * 16 + chalf * 8 + j];
                colr[j] += v;
                if (s < 8) colr0[j] += v;
            }
        }
        __syncthreads();
    }
#pragma unroll
    for (int j = 0; j < 8; j++) {
        int c = chalf * 8 + j;
        float v = (xB == 0) ? colr0[j] : colr[j];
        int oi = (c * 2 + 1) * 16384 + d * 128 + xB;
        if (bf) ((u16*)out)[oi] = f2bf(v);
        else    ((float*)out)[oi] = v;
    }
}

extern "C" void kernel_launch(void* const* d_in, const int* in_sizes, int n_in,
                              void* d_out, int out_size, void* d_ws, size_t ws_size,
                              hipStream_t stream)
{
    if (ws_size < WS_NEED) {
        sentinel_k<<<(out_size + 255) / 256, 256, 0, stream>>>((u16*)d_out, out_size);
        return;
    }
    const void* proj = d_in[0];
    const void* w1 = d_in[1]; const void* b1 = d_in[2];
    const void* w2 = d_in[3]; const void* b2 = d_in[4];
    const void* w3 = d_in[5]; const void* b3 = d_in[6];
    const void* w4 = d_in[7]; const void* b4 = d_in[8];

    u16* S0 = (u16*)d_ws;                    // vol0, later n3
    u16* S1 = S0 + VOL_ELEMS;                // raw conv outputs (y1..y4)
    u16* S2 = S1 + VOL_ELEMS;                // n1, later xb (kept for fproj)
    float* st = (float*)(S2 + VOL_ELEMS);
    int* flag = (int*)(st + 256);

    init_k<<<1, 64, 0, stream>>>(w1, st, flag);
    bcast_k<<<8192, 256, 0, stream>>>(proj, flag, S0);

    dim3 cg(8, 16, 32), cb(256);
    conv_k<<<cg, cb, 0, stream>>>(S0, w1, b1, flag, S1, st + 0);     // y1
    finalize_k<<<1, 64, 0, stream>>>(st + 0);
    norm_k<0><<<8192, 256, 0, stream>>>(S1, nullptr, st + 0, S2);    // n1
    conv_k<<<cg, cb, 0, stream>>>(S2, w2, b2, flag, S1, st + 64);    // y2
    finalize_k<<<1, 64, 0, stream>>>(st + 64);
    norm_k<1><<<8192, 256, 0, stream>>>(S1, S0, st + 64, S2);        // xb = relu(IN(y2)+vol0)
    conv_k<<<cg, cb, 0, stream>>>(S2, w3, b3, flag, S1, st + 128);   // y3
    finalize_k<<<1, 64, 0, stream>>>(st + 128);
    norm_k<0><<<8192, 256, 0, stream>>>(S1, nullptr, st + 128, S0);  // n3
    conv_k<<<cg, cb, 0, stream>>>(S0, w4, b4, flag, S1, st + 192);   // y4
    finalize_k<<<1, 64, 0, stream>>>(st + 192);
    fproj_k<<<128, 256, 0, stream>>>(S1, S2, st, flag, d_out);
}

// Round 6
// 397.195 us; speedup vs baseline: 3.5044x; 3.5044x over previous
//
#include <hip/hip_runtime.h>

// GeometryTransformation: backproject(theta=0) -> 2x resblock(conv3d 16->16 3^3,
// InstanceNorm, ReLU, residual) -> forward-project at theta in {0, pi/2}.
//
// Round-6: exploit x-constancy. vol0 = proj broadcast along x, and 3x3x3 SAME
// conv preserves x-constancy away from the x-boundary. Representation per layer:
//   interior I[d][y][c] fp32 (value of the x-constant region, valid x in [4,123])
//   mini    M[d][y][x16][c] bf16: cols 0..3 = x 0..3, col4/7 = interior ghosts,
//           cols 8..11 = x 124..127, cols 5,6,12..15 = 0 (col12=0 acts as x=128 pad)
// conv:  interior = 2D 3x3 conv with kx-summed weights; boundary = r5's verified
//        MFMA conv run on the width-16 mini volume (grid 1x16x32).
// stats: 120 * interior sums + 8 explicit boundary columns (exact partition).
// fproj: row sum = 120*v2d + 8 cols; col sums: interior i share Sum_y v2d;
//        edges from mini; i==0 sums y<64 only (HW-verified fp32 quirk).
// MFMA fragment/D layouts identical to round-5 (passed, absmax 8.0).

typedef unsigned short u16;
typedef unsigned int   u32;
using s16x8 = __attribute__((ext_vector_type(8))) short;
using f32x4 = __attribute__((ext_vector_type(4))) float;

#define IN_ELEMS 262144        // 128*128*16 fp32 interior
#define MN_ELEMS 4194304       // 128*128*16*16 u16 mini
#define WS_NEED  (3ull*IN_ELEMS*4ull + 3ull*MN_ELEMS*2ull + 4096ull)

__device__ __forceinline__ float bf2f(u16 h) {
    union { u32 u; float f; } v; v.u = ((u32)h) << 16; return v.f;
}
__device__ __forceinline__ u16 f2bf(float f) {
    union { float f; u32 u; } v; v.f = f;
    u32 u = v.u;
    return (u16)((u + 0x7fffu + ((u >> 16) & 1u)) >> 16);
}
__device__ __forceinline__ float ldin(const void* p, int i, int bf) {
    return bf ? bf2f(((const u16*)p)[i]) : ((const float*)p)[i];
}
__device__ __forceinline__ u16 ldbf(const void* p, int i, int bf) {
    return bf ? ((const u16*)p)[i] : f2bf(((const float*)p)[i]);
}
__device__ __forceinline__ void unpack8(uint4 a, float* f) {
    u32 w[4] = {a.x, a.y, a.z, a.w};
#pragma unroll
    for (int i = 0; i < 4; i++) {
        f[2*i]   = bf2f((u16)(w[i] & 0xffff));
        f[2*i+1] = bf2f((u16)(w[i] >> 16));
    }
}

// stats zero + dtype sniff (bf16 vs fp32) from w_a1 bit patterns.
__global__ void init_k(const void* __restrict__ w, float* __restrict__ st,
                       int* __restrict__ flag)
{
    const int tid = threadIdx.x;
    for (int i = tid; i < 256; i += 64) st[i] = 0.f;
    if (tid == 0) {
        const u16* p = (const u16*)w;
        int cnt = 0;
        for (int i = 0; i < 32; i++) {
            int e = (p[2 * i] >> 7) & 0xFF;
            if (e >= 64 && e <= 130) cnt++;
        }
        *flag = (cnt >= 24) ? 1 : 0;
    }
}

__global__ void sentinel_k(u16* __restrict__ out, int n)
{
    int i = blockIdx.x * 256 + threadIdx.x;
    if (i < n) out[i] = 0x4640;
}

// Build layer-0 state from proj: interior fp32 + mini (cols {0..4,7,8..11} = proj).
__global__ __launch_bounds__(256) void prep_k(const void* __restrict__ proj,
                                              const int* __restrict__ flagp,
                                              float* __restrict__ I0,
                                              u16* __restrict__ M0)
{
    const int bf = *flagp;
    const int d = blockIdx.x;
    const int tid = threadIdx.x;
    for (int i = tid; i < 2048; i += 256) {
        int y = i >> 4, c = i & 15;
        I0[(d * 128 + y) * 16 + c] = ldin(proj, c * 16384 + d * 128 + y, bf);
    }
    for (int i = tid; i < 4096; i += 256) {
        int y = i >> 5, x = (i >> 1) & 15, hh = i & 1;
        bool on = (x <= 4) | (x == 7) | (x >= 8 && x < 12);
        u32 pw[4] = {0u, 0u, 0u, 0u};
        if (on) {
#pragma unroll
            for (int j = 0; j < 4; j++) {
                int c0 = hh * 8 + 2 * j;
                u16 a = f2bf(ldin(proj, c0 * 16384 + d * 128 + y, bf));
                u16 b = f2bf(ldin(proj, (c0 + 1) * 16384 + d * 128 + y, bf));
                pw[j] = (u32)a | ((u32)b << 16);
            }
        }
        *(uint4*)(M0 + ((d * 128 + y) << 8) + (x << 4) + hh * 8) =
            make_uint4(pw[0], pw[1], pw[2], pw[3]);
    }
}

// Interior 2D conv (kx-summed weights) + bias + 120x-weighted fused stats.
// Block per d; 256 thr = 128 y x 2 co-halves.
__global__ __launch_bounds__(256) void convI_k(
    const float* __restrict__ Iin, const void* __restrict__ wgt,
    const void* __restrict__ bias, const int* __restrict__ flagp,
    float* __restrict__ Iout, float* __restrict__ st_out)
{
    __shared__ float wsum[2304];      // [kz*3+ky][ci][co]
    __shared__ float pin[3 * 2176];   // [plane][y*17+ci] (pad 17)
    __shared__ float bl[16];
    __shared__ float sred[32];
    const int bf = *flagp;
    const int d = blockIdx.x;
    const int tid = threadIdx.x;

    for (int i = tid; i < 2304; i += 256) {
        int co = i & 15, ci = (i >> 4) & 15, kk = i >> 8;
        int kz = kk / 3, ky = kk % 3;
        float s = 0.f;
#pragma unroll
        for (int kx = 0; kx < 3; kx++)
            s += ldin(wgt, (co * 16 + ci) * 27 + kz * 9 + ky * 3 + kx, bf);
        wsum[i] = s;
    }
    if (tid < 16) bl[tid] = ldin(bias, tid, bf);
    if (tid < 32) sred[tid] = 0.f;
    for (int i = tid; i < 6144; i += 256) {
        int p = i >> 11, r = i & 2047, y = r >> 4, c = r & 15;
        int zz = d + p - 1;
        float v = 0.f;
        if ((unsigned)zz < 128u) v = Iin[(zz * 128 + y) * 16 + c];
        pin[p * 2176 + y * 17 + c] = v;
    }
    __syncthreads();

    const int y = tid & 127, h = tid >> 7;
    float acc[8];
#pragma unroll
    for (int cc = 0; cc < 8; cc++) acc[cc] = bl[h * 8 + cc];
#pragma unroll
    for (int kz = 0; kz < 3; kz++) {
#pragma unroll
        for (int ky = 0; ky < 3; ky++) {
            int yy = y + ky - 1;
            if ((unsigned)yy < 128u) {
                const float* prow = &pin[kz * 2176 + yy * 17];
                const float* wrow = &wsum[(kz * 3 + ky) * 256 + h * 8];
#pragma unroll
                for (int ci = 0; ci < 16; ci++) {
                    float v = prow[ci];
#pragma unroll
                    for (int cc = 0; cc < 8; cc++)
                        acc[cc] = fmaf(v, wrow[ci * 16 + cc], acc[cc]);
                }
            }
        }
    }
    float* op = &Iout[(d * 128 + y) * 16 + h * 8];
    float s[8], q[8];
#pragma unroll
    for (int cc = 0; cc < 8; cc++) {
        op[cc] = acc[cc];
        s[cc] = acc[cc];
        q[cc] = acc[cc] * acc[cc];
    }
#pragma unroll
    for (int off = 1; off < 64; off <<= 1) {
#pragma unroll
        for (int cc = 0; cc < 8; cc++) {
            s[cc] += __shfl_down(s[cc], off, 64);
            q[cc] += __shfl_down(q[cc], off, 64);
        }
    }
    if ((tid & 63) == 0) {
#pragma unroll
        for (int cc = 0; cc < 8; cc++) {
            atomicAdd(&sred[h * 8 + cc], s[cc]);
            atomicAdd(&sred[16 + h * 8 + cc], q[cc]);
        }
    }
    __syncthreads();
    if (tid < 32) atomicAdd(&st_out[tid], 120.f * sred[tid]);
}

// Mini-volume MFMA conv (r5-verified fragments), X=16 strides, grid (1,16,32).
// Stats from real cols only (lane n in {0..3,8..11}).
__global__ __launch_bounds__(256, 4) void convM_k(
    const u16*  __restrict__ vin,   // mini [d][y][x16][ci] bf16
    const void* __restrict__ wgt, const void* __restrict__ bias,
    const int*  __restrict__ flagp,
    u16* __restrict__ outm, float* __restrict__ st_out)
{
    __shared__ uint4 tile[2160];    // [z6][y10][h2][x18]
    __shared__ float sred[32];
    const int bf  = *flagp;
    const int tid = threadIdx.x;
    const int l   = tid & 63;
    const int w   = tid >> 6;
    const int n   = l & 15;
    const int g   = l >> 4;
    const int h   = g & 1;
    const int kxs = g >> 1;

    const int y0 = blockIdx.y * 8;
    const int d0 = blockIdx.z * 4;

    if (tid < 32) sred[tid] = 0.f;

    for (int u = tid; u < 2160; u += 256) {
        int z = u / 360, r1 = u - z * 360;
        int y = r1 / 36,  r2 = r1 - y * 36;
        int x = r2 >> 1,  hh = r2 & 1;
        int gz = d0 + z - 1, gy = y0 + y - 1, gx = x - 1;
        uint4 val = make_uint4(0u, 0u, 0u, 0u);
        if ((unsigned)gz < 128u && (unsigned)gy < 128u && (unsigned)gx < 16u)
            val = *(const uint4*)(vin + (((gz << 7) + gy) << 8) + (gx << 4) + hh * 8);
        tile[((z * 10 + y) * 2 + hh) * 18 + x] = val;
    }

    s16x8 af[3][3][2];
#pragma unroll
    for (int kz = 0; kz < 3; kz++)
#pragma unroll
        for (int ky = 0; ky < 3; ky++)
#pragma unroll
            for (int grp = 0; grp < 2; grp++) {
                int kx = grp * 2 + kxs;
                s16x8 a;
#pragma unroll
                for (int e = 0; e < 8; e++) {
                    int ci = h * 8 + e;
                    u16 wv = 0;
                    if (kx <= 2)
                        wv = ldbf(wgt, n * 432 + ci * 27 + kz * 9 + ky * 3 + kx, bf);
                    a[e] = (short)wv;
                }
                af[kz][ky][grp] = a;
            }
    f32x4 binit;
#pragma unroll
    for (int r = 0; r < 4; r++) binit[r] = ldin(bias, g * 4 + r, bf);

    __syncthreads();

    f32x4 acc[8];
#pragma unroll
    for (int yl = 0; yl < 8; yl++) acc[yl] = binit;

    const int c0 = n + kxs;
    const int c1 = (c0 + 2 > 17) ? 17 : (c0 + 2);
#pragma unroll
    for (int kz = 0; kz < 3; kz++) {
        const int zt = w + kz;
#pragma unroll
        for (int yin = 0; yin < 10; yin++) {
            const int base = ((zt * 10 + yin) * 2 + h) * 18;
            s16x8 f0 = __builtin_bit_cast(s16x8, tile[base + c0]);
            s16x8 f1 = __builtin_bit_cast(s16x8, tile[base + c1]);
#pragma unroll
            for (int ky = 0; ky < 3; ky++) {
                const int yl = yin - ky;
                if (yl >= 0 && yl < 8)
                    acc[yl] = __builtin_amdgcn_mfma_f32_16x16x32_bf16(af[kz][ky][0], f0, acc[yl], 0, 0, 0);
            }
#pragma unroll
            for (int ky = 0; ky < 3; ky++) {
                const int yl = yin - ky;
                if (yl >= 0 && yl < 8)
                    acc[yl] = __builtin_amdgcn_mfma_f32_16x16x32_bf16(af[kz][ky][1], f1, acc[yl], 0, 0, 0);
            }
        }
    }

    // D: col=lane&15 -> mini x, row=g*4+r -> co. Stats only from real cols.
    const float inc = (((n >> 2) & 1) == 0) ? 1.f : 0.f;
    float sr[4] = {0.f, 0.f, 0.f, 0.f}, qr[4] = {0.f, 0.f, 0.f, 0.f};
    const int gz = d0 + w;
#pragma unroll
    for (int yl = 0; yl < 8; yl++) {
        const int gy = y0 + yl;
        u32 lo = (u32)f2bf(acc[yl][0]) | ((u32)f2bf(acc[yl][1]) << 16);
        u32 hi = (u32)f2bf(acc[yl][2]) | ((u32)f2bf(acc[yl][3]) << 16);
        *(uint2*)(outm + (((gz << 7) + gy) << 8) + (n << 4) + g * 4) = make_uint2(lo, hi);
#pragma unroll
        for (int r = 0; r < 4; r++) {
            sr[r] += inc * acc[yl][r];
            qr[r] = fmaf(inc * acc[yl][r], acc[yl][r], qr[r]);
        }
    }
#pragma unroll
    for (int off = 1; off < 16; off <<= 1) {
#pragma unroll
        for (int r = 0; r < 4; r++) {
            sr[r] += __shfl_down(sr[r], off, 16);
            qr[r] += __shfl_down(qr[r], off, 16);
        }
    }
    if (n == 0) {
#pragma unroll
        for (int r = 0; r < 4; r++) {
            atomicAdd(&sred[g * 4 + r], sr[r]);
            atomicAdd(&sred[16 + g * 4 + r], qr[r]);
        }
    }
    __syncthreads();
    if (tid < 32) atomicAdd(&st_out[tid], sred[tid]);
}

// Normalize layer: m,s from raw sums (no separate finalize). RES adds vol0(=proj).
// Rebuilds interior fp32 + mini bf16 (ghost cols 4/7 = interior, others zeroed).
template <int RES>
__global__ __launch_bounds__(256) void norm_k(
    const float* __restrict__ Iraw, const u16* __restrict__ Mraw,
    const void* __restrict__ proj, const float* __restrict__ stL,
    const int* __restrict__ flagp,
    float* __restrict__ Iout, u16* __restrict__ Mout)
{
    __shared__ float sA[32];
    const int bf = *flagp;
    const int d = blockIdx.x;
    const int tid = threadIdx.x;
    if (tid < 32) {
        const float inv = 1.f / 2097152.f;
        int c = tid & 15;
        float m = stL[c] * inv;
        if (tid < 16) sA[tid] = m;
        else          sA[tid] = rsqrtf(stL[16 + c] * inv - m * m + 1e-5f);
    }
    __syncthreads();
    for (int i = tid; i < 2048; i += 256) {
        int y = i >> 4, c = i & 15;
        float res = RES ? ldin(proj, c * 16384 + d * 128 + y, bf) : 0.f;
        float v = fmaxf((Iraw[(d * 128 + y) * 16 + c] - sA[c]) * sA[16 + c] + res, 0.f);
        Iout[(d * 128 + y) * 16 + c] = v;
    }
    for (int i = tid; i < 4096; i += 256) {
        int y = i >> 5, x = (i >> 1) & 15, hh = i & 1;
        bool realc = (x < 4) | (x >= 8 && x < 12);
        bool ghost = (x == 4) | (x == 7);
        u32 pw[4] = {0u, 0u, 0u, 0u};
        if (realc | ghost) {
            float f[8];
            if (realc) {
                uint4 raw = *(const uint4*)(Mraw + ((d * 128 + y) << 8) + (x << 4) + hh * 8);
                unpack8(raw, f);
            } else {
#pragma unroll
                for (int j = 0; j < 8; j++)
                    f[j] = Iraw[(d * 128 + y) * 16 + hh * 8 + j];
            }
            float vals[8];
#pragma unroll
            for (int j = 0; j < 8; j++) {
                int c = hh * 8 + j;
                float res = RES ? ldin(proj, c * 16384 + d * 128 + y, bf) : 0.f;
                vals[j] = fmaxf((f[j] - sA[c]) * sA[16 + c] + res, 0.f);
            }
#pragma unroll
            for (int j = 0; j < 4; j++)
                pw[j] = (u32)f2bf(vals[2*j]) | ((u32)f2bf(vals[2*j+1]) << 16);
        }
        *(uint4*)(Mout + ((d * 128 + y) << 8) + (x << 4) + hh * 8) =
            make_uint4(pw[0], pw[1], pw[2], pw[3]);
    }
}

// Final: vol2 = relu((y4 - m)s + xb). Row sums = 120*v2d + 8 cols; col sums:
// interior share Sum_y v2d; edges from mini cols; i==0 sums y<64 only.
__global__ __launch_bounds__(256) void fproj_k(
    const float* __restrict__ I4, const float* __restrict__ IXB,
    const u16* __restrict__ M4, const u16* __restrict__ MXB,
    const float* __restrict__ stL, const int* __restrict__ flagp,
    void* __restrict__ out)
{
    __shared__ float v2b[128 * 129];   // (j*16+c)*129 + y
    __shared__ float v2d[16 * 129];    // c*129 + y
    __shared__ float colsum[128], Ssum[16], C0[16];
    __shared__ float sA[32];
    const int bf = *flagp;
    const int d = blockIdx.x;
    const int tid = threadIdx.x;
    if (tid < 32) {
        const float inv = 1.f / 2097152.f;
        int c = tid & 15;
        float m = stL[c] * inv;
        if (tid < 16) sA[tid] = m;
        else          sA[tid] = rsqrtf(stL[16 + c] * inv - m * m + 1e-5f);
    }
    __syncthreads();

    const int y = tid & 127, h = tid >> 7;
#pragma unroll
    for (int cc = 0; cc < 8; cc++) {
        int c = h * 8 + cc;
        int e = (d * 128 + y) * 16 + c;
        float v = fmaxf((I4[e] - sA[c]) * sA[16 + c] + IXB[e], 0.f);
        v2d[c * 129 + y] = v;
    }
#pragma unroll
    for (int j = 0; j < 8; j++) {
        int x = (j < 4) ? j : j + 4;
        int e = ((d * 128 + y) << 8) + (x << 4) + h * 8;
        float f4[8], fx[8];
        unpack8(*(const uint4*)(M4 + e), f4);
        unpack8(*(const uint4*)(MXB + e), fx);
#pragma unroll
        for (int cc = 0; cc < 8; cc++) {
            int c = h * 8 + cc;
            float v = fmaxf((f4[cc] - sA[c]) * sA[16 + c] + fx[cc], 0.f);
            v2b[(j * 16 + c) * 129 + y] = v;
        }
    }
    __syncthreads();

    // row sums (theta=0): out[c,0,d,y]
    {
        float row[8];
#pragma unroll
        for (int cc = 0; cc < 8; cc++) row[cc] = 120.f * v2d[(h * 8 + cc) * 129 + y];
#pragma unroll
        for (int j = 0; j < 8; j++)
#pragma unroll
            for (int cc = 0; cc < 8; cc++)
                row[cc] += v2b[(j * 16 + h * 8 + cc) * 129 + y];
#pragma unroll
        for (int cc = 0; cc < 8; cc++) {
            int c = h * 8 + cc;
            int oi = (c * 2 + 0) * 16384 + d * 128 + y;
            if (bf) ((u16*)out)[oi] = f2bf(row[cc]); else ((float*)out)[oi] = row[cc];
        }
    }

    // column sums
    if (tid < 128) {
        int j = tid >> 4, c = tid & 15;
        float s = 0.f, s0 = 0.f;
        for (int yy = 0; yy < 128; yy++) {
            float v = v2b[(j * 16 + c) * 129 + yy];
            s += v;
            if (yy < 64) s0 += v;
        }
        colsum[j * 16 + c] = s;
        if (j == 0) C0[c] = s0;
    } else if (tid < 144) {
        int c = tid - 128;
        float s = 0.f;
        for (int yy = 0; yy < 128; yy++) s += v2d[c * 129 + yy];
        Ssum[c] = s;
    }
    __syncthreads();

    for (int i = tid; i < 2048; i += 256) {
        int c = i >> 7, u = i & 127;
        float v;
        if (u == 0)        v = C0[c];
        else if (u < 4)    v = colsum[u * 16 + c];
        else if (u >= 124) v = colsum[(u - 120) * 16 + c];
        else               v = Ssum[c];
        int oi = (c * 2 + 1) * 16384 + d * 128 + u;
        if (bf) ((u16*)out)[oi] = f2bf(v); else ((float*)out)[oi] = v;
    }
}

extern "C" void kernel_launch(void* const* d_in, const int* in_sizes, int n_in,
                              void* d_out, int out_size, void* d_ws, size_t ws_size,
                              hipStream_t stream)
{
    if (ws_size < WS_NEED) {
        sentinel_k<<<(out_size + 255) / 256, 256, 0, stream>>>((u16*)d_out, out_size);
        return;
    }
    const void* proj = d_in[0];
    const void* w1 = d_in[1]; const void* b1 = d_in[2];
    const void* w2 = d_in[3]; const void* b2 = d_in[4];
    const void* w3 = d_in[5]; const void* b3 = d_in[6];
    const void* w4 = d_in[7]; const void* b4 = d_in[8];

    float* I_A  = (float*)d_ws;
    float* I_B  = I_A + IN_ELEMS;
    float* I_XB = I_B + IN_ELEMS;
    u16*   M_A  = (u16*)(I_XB + IN_ELEMS);
    u16*   M_B  = M_A + MN_ELEMS;
    u16*   M_XB = M_B + MN_ELEMS;
    float* st   = (float*)(M_XB + MN_ELEMS);
    int*   flag = (int*)(st + 256);

    init_k<<<1, 64, 0, stream>>>(w1, st, flag);
    prep_k<<<128, 256, 0, stream>>>(proj, flag, I_A, M_A);

    dim3 mg(1, 16, 32), cb(256);
    // L1 = conv_a1
    convI_k<<<128, cb, 0, stream>>>(I_A, w1, b1, flag, I_B, st + 0);
    convM_k<<<mg, cb, 0, stream>>>(M_A, w1, b1, flag, M_B, st + 0);
    norm_k<0><<<128, cb, 0, stream>>>(I_B, M_B, proj, st + 0, flag, I_A, M_A);   // n1
    // L2 = conv_a2
    convI_k<<<128, cb, 0, stream>>>(I_A, w2, b2, flag, I_B, st + 64);
    convM_k<<<mg, cb, 0, stream>>>(M_A, w2, b2, flag, M_B, st + 64);
    norm_k<1><<<128, cb, 0, stream>>>(I_B, M_B, proj, st + 64, flag, I_XB, M_XB); // xb
    // L3 = conv_b1
    convI_k<<<128, cb, 0, stream>>>(I_XB, w3, b3, flag, I_B, st + 128);
    convM_k<<<mg, cb, 0, stream>>>(M_XB, w3, b3, flag, M_B, st + 128);
    norm_k<0><<<128, cb, 0, stream>>>(I_B, M_B, proj, st + 128, flag, I_A, M_A);  // n3
    // L4 = conv_b2
    convI_k<<<128, cb, 0, stream>>>(I_A, w4, b4, flag, I_B, st + 192);
    convM_k<<<mg, cb, 0, stream>>>(M_A, w4, b4, flag, M_B, st + 192);
    // final projection
    fproj_k<<<128, cb, 0, stream>>>(I_B, I_XB, M_B, M_XB, st + 192, flag, d_out);
}